// Round 1
// baseline (30.724 us; speedup 1.0000x reference)
//
#include <hip/hip_runtime.h>

// Problem constants (from reference setup_inputs)
#define BATCH    8
#define FH       64
#define FW       64
#define FC       256
#define NUM_ROIS 128
#define POOLSZ   7

// Output: [B, NUM_ROIS, 7, 7, C] f32. Total cells = B*NUM_ROIS*49 = 50176.
// One 64-lane group per cell; lane q handles channels [4q, 4q+4).
// Flat thread idx: cell = idx>>6, q = idx&63. Output float4 offset == idx.

__global__ __launch_bounds__(256) void roi_crop_resize_kernel(
    const float* __restrict__ fmap,   // [B,H,W,C]
    const float* __restrict__ rois,   // [B,NUM_ROIS,4] (x1,y1,x2,y2)
    float* __restrict__ out)          // [B,NUM_ROIS,7,7,C]
{
    const int idx = blockIdx.x * blockDim.x + threadIdx.x;
    const int q    = idx & 63;        // float4 channel group 0..63
    const int cell = idx >> 6;        // 0..50175

    const int px = cell % POOLSZ;
    const int t  = cell / POOLSZ;
    const int py = t % POOLSZ;
    const int roi_flat = t / POOLSZ;  // 0..1023
    const int b = roi_flat >> 7;      // / NUM_ROIS

    // rois row: (x1, y1, x2, y2)
    const float4 r4 = reinterpret_cast<const float4*>(rois)[roi_flat];

    // Replicate reference arithmetic exactly:
    // boxes = (y1/63, x1/63, y2/63, x2/63); in_y = y1n*63 + iy*((y2n-y1n)*63/6)
    const float inv63 = 1.0f / 63.0f;
    const float y1n = r4.y * inv63;
    const float x1n = r4.x * inv63;
    const float y2n = r4.w * inv63;
    const float x2n = r4.z * inv63;

    const float in_y = y1n * 63.0f + (float)py * (((y2n - y1n) * 63.0f) / 6.0f);
    const float in_x = x1n * 63.0f + (float)px * (((x2n - x1n) * 63.0f) / 6.0f);

    const bool valid = (in_y >= 0.0f) && (in_y <= 63.0f) &&
                       (in_x >= 0.0f) && (in_x <= 63.0f);

    const float top  = floorf(in_y);
    const float left = floorf(in_x);
    const float yl = in_y - top;
    const float xl = in_x - left;

    // clip(float,0,63) then int cast — values are integer-valued floats
    const int ti = min(max((int)top,         0), FH - 1);
    const int bi = min(max((int)ceilf(in_y), 0), FH - 1);
    const int li = min(max((int)left,        0), FW - 1);
    const int ri = min(max((int)ceilf(in_x), 0), FW - 1);

    // Feature map in float4 units: (((b*64 + y)*64 + x)*256 + 4q)/4
    const float4* __restrict__ f4 = reinterpret_cast<const float4*>(fmap);
    const int rowb = b << 6;  // b*64
    const int itl = (((rowb + ti) << 6) + li) * 64 + q;
    const int itr = (((rowb + ti) << 6) + ri) * 64 + q;
    const int ibl = (((rowb + bi) << 6) + li) * 64 + q;
    const int ibr = (((rowb + bi) << 6) + ri) * 64 + q;

    const float4 vtl = f4[itl];
    const float4 vtr = f4[itr];
    const float4 vbl = f4[ibl];
    const float4 vbr = f4[ibr];

    float4 o;
    {
        float tv, bv;
        tv = vtl.x + (vtr.x - vtl.x) * xl;
        bv = vbl.x + (vbr.x - vbl.x) * xl;
        o.x = tv + (bv - tv) * yl;
        tv = vtl.y + (vtr.y - vtl.y) * xl;
        bv = vbl.y + (vbr.y - vbl.y) * xl;
        o.y = tv + (bv - tv) * yl;
        tv = vtl.z + (vtr.z - vtl.z) * xl;
        bv = vbl.z + (vbr.z - vbl.z) * xl;
        o.z = tv + (bv - tv) * yl;
        tv = vtl.w + (vtr.w - vtl.w) * xl;
        bv = vbl.w + (vbr.w - vbl.w) * xl;
        o.w = tv + (bv - tv) * yl;
    }
    if (!valid) { o.x = 0.0f; o.y = 0.0f; o.z = 0.0f; o.w = 0.0f; }

    reinterpret_cast<float4*>(out)[idx] = o;
}

extern "C" void kernel_launch(void* const* d_in, const int* in_sizes, int n_in,
                              void* d_out, int out_size, void* d_ws, size_t ws_size,
                              hipStream_t stream) {
    const float* fmap = (const float*)d_in[0];
    const float* rois = (const float*)d_in[1];
    float* out = (float*)d_out;

    // total float4 outputs = B*NUM_ROIS*49*64 = 3,211,264
    const int total_threads = BATCH * NUM_ROIS * POOLSZ * POOLSZ * 64;
    const int block = 256;
    const int grid = total_threads / block;  // 12544

    roi_crop_resize_kernel<<<grid, block, 0, stream>>>(fmap, rois, out);
}

// Round 3
// 17.355 us; speedup vs baseline: 1.7703x; 1.7703x over previous
//
#include <hip/hip_runtime.h>

// Problem constants (from reference setup_inputs)
#define BATCH    8
#define FH       64
#define FW       64
#define FC       256
#define NUM_ROIS 128
#define POOLSZ   7

#define NXCD     8
#define NBLOCKS  12544             // total blocks, 8 batches x 1568
#define CHUNK    (NBLOCKS / NXCD)  // 1568 = one batch's blocks

typedef float  fx4 __attribute__((ext_vector_type(4)));  // native clang vector

// Output: [B, NUM_ROIS, 7, 7, C] f32. Total cells = B*NUM_ROIS*49 = 50176.
// One 64-lane group per cell; lane q handles channels [4q, 4q+4).
// XCD-aware swizzle: dispatch round-robins blockIdx across 8 XCDs; remap so
// XCD i executes the contiguous chunk [i*1568, (i+1)*1568) == batch i exactly.
// Per-XCD read working set = 4.2 MB fmap slice ~= one L2.

__global__ __launch_bounds__(256) void roi_crop_resize_kernel(
    const float* __restrict__ fmap,   // [B,H,W,C]
    const float* __restrict__ rois,   // [B,NUM_ROIS,4] (x1,y1,x2,y2)
    float* __restrict__ out)          // [B,NUM_ROIS,7,7,C]
{
    const int bid = blockIdx.x;
    const int swz = (bid & (NXCD - 1)) * CHUNK + (bid >> 3);  // bijective, nwg%8==0
    const int idx = swz * blockDim.x + threadIdx.x;

    const int q    = idx & 63;        // float4 channel group 0..63
    const int cell = idx >> 6;        // 0..50175

    const int px = cell % POOLSZ;
    const int t  = cell / POOLSZ;
    const int py = t % POOLSZ;
    const int roi_flat = t / POOLSZ;  // 0..1023
    const int b = roi_flat >> 7;      // / NUM_ROIS

    // rois row: (x1, y1, x2, y2)
    const fx4 r4 = reinterpret_cast<const fx4*>(rois)[roi_flat];

    // Replicate reference arithmetic exactly:
    // boxes = (y1/63, x1/63, y2/63, x2/63); in_y = y1n*63 + iy*((y2n-y1n)*63/6)
    const float inv63 = 1.0f / 63.0f;
    const float x1n = r4.x * inv63;
    const float y1n = r4.y * inv63;
    const float x2n = r4.z * inv63;
    const float y2n = r4.w * inv63;

    const float in_y = y1n * 63.0f + (float)py * (((y2n - y1n) * 63.0f) / 6.0f);
    const float in_x = x1n * 63.0f + (float)px * (((x2n - x1n) * 63.0f) / 6.0f);

    const bool valid = (in_y >= 0.0f) && (in_y <= 63.0f) &&
                       (in_x >= 0.0f) && (in_x <= 63.0f);

    const float top  = floorf(in_y);
    const float left = floorf(in_x);
    const float yl = in_y - top;
    const float xl = in_x - left;

    const int ti = min(max((int)top,         0), FH - 1);
    const int bi = min(max((int)ceilf(in_y), 0), FH - 1);
    const int li = min(max((int)left,        0), FW - 1);
    const int ri = min(max((int)ceilf(in_x), 0), FW - 1);

    // Feature map in float4 units: (((b*64 + y)*64 + x)*256 + 4q)/4
    const fx4* __restrict__ f4 = reinterpret_cast<const fx4*>(fmap);
    const int rowb = b << 6;  // b*64
    const int itl = (((rowb + ti) << 6) + li) * 64 + q;
    const int itr = (((rowb + ti) << 6) + ri) * 64 + q;
    const int ibl = (((rowb + bi) << 6) + li) * 64 + q;
    const int ibr = (((rowb + bi) << 6) + ri) * 64 + q;

    const fx4 vtl = f4[itl];
    const fx4 vtr = f4[itr];
    const fx4 vbl = f4[ibl];
    const fx4 vbr = f4[ibr];

    const fx4 top_v = vtl + (vtr - vtl) * xl;
    const fx4 bot_v = vbl + (vbr - vbl) * xl;
    fx4 o = top_v + (bot_v - top_v) * yl;
    if (!valid) o = (fx4)0.0f;

    // Non-temporal: output is write-once, keep it from evicting fmap in L2.
    __builtin_nontemporal_store(o, &reinterpret_cast<fx4*>(out)[idx]);
}

extern "C" void kernel_launch(void* const* d_in, const int* in_sizes, int n_in,
                              void* d_out, int out_size, void* d_ws, size_t ws_size,
                              hipStream_t stream) {
    const float* fmap = (const float*)d_in[0];
    const float* rois = (const float*)d_in[1];
    float* out = (float*)d_out;

    // total float4 outputs = B*NUM_ROIS*49*64 = 3,211,264 threads / 256 = 12544 blocks
    const int block = 256;
    roi_crop_resize_kernel<<<NBLOCKS, block, 0, stream>>>(fmap, rois, out);
}